// Round 5
// baseline (244.143 us; speedup 1.0000x reference)
//
#include <hip/hip_runtime.h>
#include <hip/hip_bf16.h>

// Problem constants (fixed by setup_inputs)
#define BS   4
#define NQ   6400
#define DIMS 256
#define NH   8
#define NP   4
#define GW   80
#define GH   80

typedef __hip_bfloat16 bf16;
typedef unsigned short ushort;
typedef __attribute__((ext_vector_type(8))) short short8;   // 8 bf16 (MFMA A/B frag)
typedef __attribute__((ext_vector_type(4))) float floatx4;  // MFMA C/D frag

union bfu { bf16 h; ushort s; };
__device__ __forceinline__ ushort f2bs(float x) { bfu u; u.h = __float2bfloat16(x); return u.s; }
__device__ __forceinline__ float bs2f(ushort s) { return __uint_as_float(((unsigned)s) << 16); }
__device__ __forceinline__ float ldin(const void* p, size_t i, int isf) {
    return isf ? ((const float*)p)[i] : bs2f(((const ushort*)p)[i]);
}

// async global->LDS, 16B per lane; LDS dest = wave-uniform base + lane*16
__device__ __forceinline__ void glds16(const void* g, const void* l) {
    __builtin_amdgcn_global_load_lds(
        (const __attribute__((address_space(1))) unsigned int*)g,
        (__attribute__((address_space(3))) unsigned int*)(unsigned)(uintptr_t)l,
        16, 0, 0);
}

// ---------------------------------------------------------------------------
// dtype detector: f32-packed data read as bf16 shows impossible exponents.
// ---------------------------------------------------------------------------
__global__ void detect_k(const ushort* __restrict__ q, int* flag) {
    __shared__ int s;
    if (threadIdx.x == 0) s = 0;
    __syncthreads();
    int bad = 0;
    for (int j = 0; j < 16; ++j) {
        ushort v = q[threadIdx.x * 16 + j];
        int e = (v >> 7) & 0xFF;
        if (e > 160) bad = 1;
    }
    if (bad) atomicOr(&s, 1);
    __syncthreads();
    if (threadIdx.x == 0) *flag = s;
}

// ---------------------------------------------------------------------------
// Weight prep: transpose+convert weights to bf16 B^T[n][k]; biases to f32.
// ---------------------------------------------------------------------------
__global__ void wprep_k(
    const void* __restrict__ Wv, const void* __restrict__ bv,
    const void* __restrict__ Woff, const void* __restrict__ boff,
    const void* __restrict__ Wattn, const void* __restrict__ battn,
    const void* __restrict__ Wo, const void* __restrict__ bo,
    const int* __restrict__ flagp,
    ushort* __restrict__ WvT, ushort* __restrict__ WoaT, ushort* __restrict__ WoT,
    float* __restrict__ biasv, float* __restrict__ biasoa, float* __restrict__ biaso)
{
    const int isf = *flagp;
    const int i = blockIdx.x * 256 + threadIdx.x;
    const int n1 = 256 * 256, n2 = n1 + 192 * 512, n3 = n2 + 256 * 256;
    const int n4 = n3 + 256, n5 = n4 + 192, n6 = n5 + 256;
    if (i < n1) {
        int n = i >> 8, k = i & 255;
        WvT[i] = f2bs(ldin(Wv, (size_t)k * 256 + n, isf));
    } else if (i < n2) {
        int j = i - n1, n = j >> 9, k = j & 511;
        float v = (n < 128) ? ldin(Woff, (size_t)k * 128 + n, isf)
                            : ldin(Wattn, (size_t)k * 64 + (n - 128), isf);
        WoaT[j] = f2bs(v);
    } else if (i < n3) {
        int j = i - n2, n = j >> 8, k = j & 255;
        WoT[j] = f2bs(ldin(Wo, (size_t)k * 256 + n, isf));
    } else if (i < n4) {
        biasv[i - n3] = ldin(bv, i - n3, isf);
    } else if (i < n5) {
        int j = i - n4;
        biasoa[j] = (j < 128) ? ldin(boff, j, isf) : ldin(battn, j - 128, isf);
    } else if (i < n6) {
        biaso[i - n5] = ldin(bo, i - n5, isf);
    }
}

// ---------------------------------------------------------------------------
// Convert query/voxbev to bf16 (or plain copy if already bf16). 16B/thread.
// ---------------------------------------------------------------------------
__global__ __launch_bounds__(256) void cvt_k(
    const void* __restrict__ query, const void* __restrict__ voxbev,
    const int* __restrict__ flagp,
    uint4* __restrict__ qb, uint4* __restrict__ vbv)
{
    const int isf = *flagp;
    const int t = blockIdx.x * 256 + threadIdx.x;   // 2 * 819200 chunks of 8 elems
    const int half = 819200;
    const void* src = (t < half) ? query : voxbev;
    uint4* dst = (t < half) ? qb : vbv;
    const int j = (t < half) ? t : t - half;
    uint4 o;
    if (isf) {
        const float4* s = (const float4*)src + (size_t)j * 2;
        float4 a = s[0], b = s[1];
        o.x = ((unsigned)f2bs(a.y) << 16) | f2bs(a.x);
        o.y = ((unsigned)f2bs(a.w) << 16) | f2bs(a.z);
        o.z = ((unsigned)f2bs(b.y) << 16) | f2bs(b.x);
        o.w = ((unsigned)f2bs(b.w) << 16) | f2bs(b.z);
    } else {
        o = ((const uint4*)src)[j];
    }
    dst[j] = o;
}

// ---------------------------------------------------------------------------
// MFMA GEMM, m97 structure: 128(M) x BN tile, BK=32, global_load_lds staging,
// 4 waves 2x2 (each 64 x BN/2), 16x16x32 bf16 MFMA, LDS-bounced epilogue.
// A sources (bf16): A_VAL interleaved qb/vbv rows; A_QCAT [value row | qb row]
// (K=512); A_PLAIN flat Apl.
// OMODE: O_BF16 -> bf16 C with bias (coalesced dwordx4 stores)
//        O_FINAL -> C = acc + bias + residual(query raw), f32 or bf16 per flag
// ---------------------------------------------------------------------------
enum { A_VAL = 0, A_QCAT = 1, A_PLAIN = 2 };
enum { O_BF16 = 0, O_FINAL = 1 };

template <int AMODE, int OMODE, int BN>
__global__ __launch_bounds__(256) void mgemm_k(
    const ushort* __restrict__ Apl, const ushort* __restrict__ BT,
    const float* __restrict__ biasf, void* __restrict__ C,
    const ushort* __restrict__ qb, const ushort* __restrict__ vbv,
    const void* __restrict__ resid, const int* __restrict__ flagp,
    int N, int K)
{
    constexpr int ASZ = 128 * 32;                    // shorts
    constexpr int BSZ = BN * 32;
    constexpr int CB  = 128 * BN;                    // bf16 bounce shorts
    constexpr int CF  = (OMODE == O_FINAL) ? 128 * 64 * 2 : 0;  // f32 bounce, in shorts
    constexpr int SM  = (ASZ + BSZ > CB ? ASZ + BSZ : CB) > CF
                      ? (ASZ + BSZ > CB ? ASZ + BSZ : CB) : CF;
    __shared__ __align__(16) short smem[SM];

    const int isf = *flagp;
    const int tid = threadIdx.x;
    const int bm = blockIdx.y * 128;
    const int bn = blockIdx.x * BN;
    const int lane = tid & 63, wv = tid >> 6;

    // ---- staging addresses: chunk = 16 rows x 32 shorts = 1024 B = 1 wave op
    const ushort* alo[2]; const ushort* ahi[2];
    #pragma unroll
    for (int c = 0; c < 2; ++c) {
        const int row = bm + (wv * 2 + c) * 16 + (lane >> 2);
        const int kp = (lane & 3) * 8;
        if (AMODE == A_PLAIN) {
            alo[c] = Apl + (size_t)row * K + kp;
        } else {
            const int bq = row / NQ, q = row - bq * NQ;
            if (AMODE == A_VAL) {
                alo[c] = ((bq & 1) ? vbv : qb) + (size_t)((bq >> 1) * NQ + q) * DIMS + kp;
            } else {
                alo[c] = ((bq & 1) ? vbv : qb) + (size_t)((bq >> 1) * NQ + q) * DIMS + kp;
                ahi[c] = qb + (size_t)(bq * NQ + q) * DIMS + kp;
            }
        }
    }
    constexpr int BCH = BN / 64;                     // B chunks per wave
    const ushort* bp[BCH];
    #pragma unroll
    for (int c = 0; c < BCH; ++c) {
        const int row = (wv * BCH + c) * 16 + (lane >> 2);
        bp[c] = BT + (size_t)(bn + row) * K + (lane & 3) * 8;
    }

    const int wm = (wv & 1) * 64, wn = (wv >> 1) * (BN / 2);
    const int fr = lane & 15, fq = (lane >> 4) * 8;
    constexpr int NT = BN / 32;
    floatx4 acc[4][NT] = {};

    for (int k0 = 0; k0 < K; k0 += 32) {
        #pragma unroll
        for (int c = 0; c < 2; ++c) {
            const ushort* g;
            if (AMODE == A_QCAT) g = (k0 < DIMS) ? alo[c] + k0 : ahi[c] + (k0 - DIMS);
            else                 g = alo[c] + k0;
            glds16(g, &smem[(wv * 2 + c) * 512]);
        }
        #pragma unroll
        for (int c = 0; c < BCH; ++c)
            glds16(bp[c] + k0, &smem[ASZ + (wv * BCH + c) * 512]);
        __syncthreads();

        short8 af[4], bf[NT];
        #pragma unroll
        for (int mt = 0; mt < 4; ++mt)
            af[mt] = *(const short8*)&smem[(wm + mt * 16 + fr) * 32 + fq];
        #pragma unroll
        for (int nt = 0; nt < NT; ++nt)
            bf[nt] = *(const short8*)&smem[ASZ + (wn + nt * 16 + fr) * 32 + fq];
        #pragma unroll
        for (int mt = 0; mt < 4; ++mt)
            #pragma unroll
            for (int nt = 0; nt < NT; ++nt)
                acc[mt][nt] = __builtin_amdgcn_mfma_f32_16x16x32_bf16(
                    af[mt], bf[nt], acc[mt][nt], 0, 0, 0);
        __syncthreads();
    }

    // ---- epilogue (C/D layout: col=lane&15, row=(lane>>4)*4+reg)
    const int col = lane & 15, rq = (lane >> 4) * 4;
    if (OMODE == O_BF16) {
        #pragma unroll
        for (int mt = 0; mt < 4; ++mt)
            #pragma unroll
            for (int nt = 0; nt < NT; ++nt)
                #pragma unroll
                for (int r = 0; r < 4; ++r)
                    smem[(wm + mt * 16 + rq + r) * BN + wn + nt * 16 + col] =
                        (short)f2bs(acc[mt][nt][r]);
        __syncthreads();
        // coalesced store: thread -> row tid>>1, half-row (tid&1)*BN/2 shorts
        const int row = tid >> 1, cs = (tid & 1) * (BN / 2);
        const size_t gbase = (size_t)(bm + row) * N + bn + cs;
        #pragma unroll
        for (int v = 0; v < BN / 16; ++v) {          // 8 shorts per chunk
            unsigned o[4];
            #pragma unroll
            for (int e = 0; e < 4; ++e) {
                const int j = v * 8 + e * 2;
                float x0 = bs2f((ushort)smem[row * BN + cs + j])     + biasf[bn + cs + j];
                float x1 = bs2f((ushort)smem[row * BN + cs + j + 1]) + biasf[bn + cs + j + 1];
                o[e] = ((unsigned)f2bs(x1) << 16) | f2bs(x0);
            }
            *(uint4*)((ushort*)C + gbase + v * 8) = *(uint4*)o;
        }
    } else {
        // two passes of 64 cols through f32 LDS
        float* cf = (float*)smem;
        #pragma unroll
        for (int pass = 0; pass < 2; ++pass) {
            if ((wv >> 1) == pass) {
                #pragma unroll
                for (int mt = 0; mt < 4; ++mt)
                    #pragma unroll
                    for (int nt = 0; nt < NT; ++nt)
                        #pragma unroll
                        for (int r = 0; r < 4; ++r)
                            cf[(wm + mt * 16 + rq + r) * 64 + nt * 16 + col] = acc[mt][nt][r];
            }
            __syncthreads();
            const int row = tid >> 1, cs = (tid & 1) * 32;
            const int grow = bm + row, gc0 = bn + pass * 64 + cs;
            const size_t gbase = (size_t)grow * N + gc0;
            #pragma unroll
            for (int v = 0; v < 8; ++v) {
                float4 o;
                #pragma unroll
                for (int e = 0; e < 4; ++e) {
                    const int j = v * 4 + e;
                    ((float*)&o)[e] = cf[row * 64 + cs + j] + biasf[gc0 + j]
                                    + ldin(resid, gbase + j, isf);
                }
                if (isf) *(float4*)((float*)C + gbase + v * 4) = o;
                else {
                    ushort* d = (ushort*)C + gbase + v * 4;
                    d[0] = f2bs(o.x); d[1] = f2bs(o.y); d[2] = f2bs(o.z); d[3] = f2bs(o.w);
                }
            }
            __syncthreads();
        }
    }
}

// ---------------------------------------------------------------------------
// Fused softmax + coords + bilinear sampling + queue mean.
// Block = 8 queries of ONE batch (XCD-swizzled). Phase 2: thread = (lq,h,d8),
// dwordx4 gathers (8 dims), 8 independent accumulators.
// ---------------------------------------------------------------------------
__global__ __launch_bounds__(256) void sample_k(
    const ushort* __restrict__ v,        // [BS*2, NQ, 256] bf16
    const ushort* __restrict__ offraw,   // [BS*NQ, 192] bf16 (offs 0-127, logits 128-191)
    const void* __restrict__ refpts,     // [BS*2, NQ, 1, 2] input dtype
    const int* __restrict__ flagp,
    ushort* __restrict__ sampled)        // [BS*NQ, 256] bf16
{
    const int isf = *flagp;
    __shared__ float sx[8][2][8][4], sy[8][2][8][4], sw[8][2][8][4];
    const int tid = threadIdx.x;
    const int j = blockIdx.x;
    const int slot = j & 7;
    const int b = slot >> 1;
    const int idx = ((j >> 3) << 1) + (slot & 1);    // 0..799
    const int q0 = idx * 8;

    if (tid < 128) {
        const int lq = tid >> 4, queue = (tid >> 3) & 1, h = tid & 7;
        const int q = q0 + lq;
        const int gq = b * NQ + q;
        const ushort* row = offraw + (size_t)gq * 192;
        const ushort* al = row + 128 + h * 8 + queue * 4;
        float l0 = bs2f(al[0]), l1 = bs2f(al[1]), l2 = bs2f(al[2]), l3 = bs2f(al[3]);
        float mx = fmaxf(fmaxf(l0, l1), fmaxf(l2, l3));
        float e0 = __expf(l0 - mx), e1 = __expf(l1 - mx);
        float e2 = __expf(l2 - mx), e3 = __expf(l3 - mx);
        float inv = 0.5f / (e0 + e1 + e2 + e3);      // fold queue-mean 0.5
        const int bq = b * 2 + queue;
        const float rx = ldin(refpts, ((size_t)bq * NQ + q) * 2 + 0, isf);
        const float ry = ldin(refpts, ((size_t)bq * NQ + q) * 2 + 1, isf);
        const ushort* od = row + h * 16 + queue * 8;
        float ww[4] = { e0 * inv, e1 * inv, e2 * inv, e3 * inv };
        #pragma unroll
        for (int p = 0; p < NP; ++p) {
            sx[lq][queue][h][p] = rx * (float)GW + bs2f(od[p * 2 + 0]) - 0.5f;
            sy[lq][queue][h][p] = ry * (float)GH + bs2f(od[p * 2 + 1]) - 0.5f;
            sw[lq][queue][h][p] = ww[p];
        }
    }
    __syncthreads();

    const int lq = tid >> 5, h = (tid >> 2) & 7, d8 = tid & 3;
    const int gq = b * NQ + q0 + lq;
    const int doff = h * 32 + d8 * 8;
    float a[8] = {};
    #pragma unroll
    for (int queue = 0; queue < 2; ++queue) {
        const ushort* vb = v + (size_t)(b * 2 + queue) * NQ * DIMS;
        #pragma unroll
        for (int p = 0; p < NP; ++p) {
            const float x = sx[lq][queue][h][p];
            const float y = sy[lq][queue][h][p];
            const float w = sw[lq][queue][h][p];
            const float x0f = floorf(x), y0f = floorf(y);
            const float dx = x - x0f, dy = y - y0f;
            const int x0 = (int)x0f, y0 = (int)y0f;
            const float c00 = w * (1.0f - dx) * (1.0f - dy);
            const float c10 = w * dx * (1.0f - dy);
            const float c01 = w * (1.0f - dx) * dy;
            const float c11 = w * dx * dy;
#define CORNER(xi, yi, cw)                                                        \
            if ((unsigned)(xi) < (unsigned)GW && (unsigned)(yi) < (unsigned)GH) { \
                const uint4 u = *(const uint4*)&vb[(size_t)((yi) * GW + (xi)) * DIMS + doff]; \
                a[0] += (cw) * bs2f((ushort)u.x); a[1] += (cw) * bs2f((ushort)(u.x >> 16)); \
                a[2] += (cw) * bs2f((ushort)u.y); a[3] += (cw) * bs2f((ushort)(u.y >> 16)); \
                a[4] += (cw) * bs2f((ushort)u.z); a[5] += (cw) * bs2f((ushort)(u.z >> 16)); \
                a[6] += (cw) * bs2f((ushort)u.w); a[7] += (cw) * bs2f((ushort)(u.w >> 16)); \
            }
            CORNER(x0,     y0,     c00)
            CORNER(x0 + 1, y0,     c10)
            CORNER(x0,     y0 + 1, c01)
            CORNER(x0 + 1, y0 + 1, c11)
#undef CORNER
        }
    }
    uint4 o;
    o.x = ((unsigned)f2bs(a[1]) << 16) | f2bs(a[0]);
    o.y = ((unsigned)f2bs(a[3]) << 16) | f2bs(a[2]);
    o.z = ((unsigned)f2bs(a[5]) << 16) | f2bs(a[4]);
    o.w = ((unsigned)f2bs(a[7]) << 16) | f2bs(a[6]);
    *(uint4*)&sampled[(size_t)gq * DIMS + doff] = o;
}

// ---------------------------------------------------------------------------
extern "C" void kernel_launch(void* const* d_in, const int* in_sizes, int n_in,
                              void* d_out, int out_size, void* d_ws, size_t ws_size,
                              hipStream_t stream)
{
    const void* query  = d_in[0];
    const void* voxbev = d_in[1];
    const void* refpts = d_in[2];
    // d_in[3] spatial_shapes=[[80,80]], d_in[4] level_start_index=[0]: hardcoded
    const void* Wv   = d_in[5];  const void* bv    = d_in[6];
    const void* Woff = d_in[7];  const void* boff  = d_in[8];
    const void* Wattn= d_in[9];  const void* battn = d_in[10];
    const void* Wo   = d_in[11]; const void* bo    = d_in[12];

    // workspace (~59.8 MB; sampled aliases qb, which is dead after GEMM 2)
    char* p = (char*)d_ws;
    int* flag = (int*)p;             p += 256;
    ushort* WvT  = (ushort*)p;       p += 256 * 256 * 2;
    ushort* WoaT = (ushort*)p;       p += 192 * 512 * 2;
    ushort* WoT  = (ushort*)p;       p += 256 * 256 * 2;
    float* biasv  = (float*)p;       p += 1024;
    float* biasoa = (float*)p;       p += 1024;
    float* biaso  = (float*)p;       p += 1024;
    ushort* qb   = (ushort*)p;       p += (size_t)BS * NQ * DIMS * 2;       // 13.1 MB
    ushort* vbv  = (ushort*)p;       p += (size_t)BS * NQ * DIMS * 2;       // 13.1 MB
    ushort* v_ws = (ushort*)p;       p += (size_t)2 * BS * NQ * DIMS * 2;   // 26.2 MB
    ushort* offraw = (ushort*)p;     p += (size_t)BS * NQ * 192 * 2;        //  9.8 MB
    ushort* sampled = qb;            // alias: qb dead after GEMM 2

    detect_k<<<1, 256, 0, stream>>>((const ushort*)query, flag);
    wprep_k<<<899, 256, 0, stream>>>(Wv, bv, Woff, boff, Wattn, battn, Wo, bo,
                                     flag, WvT, WoaT, WoT, biasv, biasoa, biaso);
    cvt_k<<<6400, 256, 0, stream>>>(query, voxbev, flag, (uint4*)qb, (uint4*)vbv);

    // 1. v = interleave(q,v) @ Wv + bv   [51200,256] bf16
    mgemm_k<A_VAL, O_BF16, 128><<<dim3(2, 400), 256, 0, stream>>>(
        nullptr, WvT, biasv, (void*)v_ws, qb, vbv, nullptr, flag, 256, 256);

    // 2. offraw = qcat @ [Woff|Wattn] + bias   [25600,192] bf16
    mgemm_k<A_QCAT, O_BF16, 64><<<dim3(3, 200), 256, 0, stream>>>(
        nullptr, WoaT, biasoa, (void*)offraw, qb, vbv, nullptr, flag, 192, 512);

    // 3. fused softmax + coords + bilinear sampling + queue mean
    sample_k<<<3200, 256, 0, stream>>>(v_ws, offraw, refpts, flag, sampled);

    // 4. out = sampled @ Wo + bo + query   [25600,256], dtype per flag
    mgemm_k<A_PLAIN, O_FINAL, 128><<<dim3(2, 200), 256, 0, stream>>>(
        sampled, WoT, biaso, d_out, qb, vbv, query, flag, 256, 256);
}